// Round 6
// baseline (159.344 us; speedup 1.0000x reference)
//
#include <hip/hip_runtime.h>

// YOLO layer: input [B, A*(5+C), H, W] fp32 -> (boxes [B,N,1,4], confs [B,N,C]) fp32
// B=64, A=3, C=80, H=W=76, N=A*H*W=17328
// d_out = boxes flat (B*N*4) then confs flat (B*N*C)
//
// R5->R6: 4 y-rows per block -> every channel segment is 1216B and starts
// 64B-aligned (4*304 % 64 == 0): ZERO read over-fetch, no reliance on L2
// boundary-line reuse. Sigmoid-path channels staged bf16 (err ~3e-3),
// exp-path (wh) kept f32. LDS 54.2KB -> 3 blocks/CU x 8 waves = 24 waves/CU
// (R4/R5 showed 24 vs 32 waves is performance-neutral).

#define Bn 64
#define An 3
#define Cn 80
#define Hn 76
#define Wn 76
#define HW (Hn * Wn)              // 5776
#define Nn (An * HW)              // 17328
#define CHn (5 + Cn)              // 85
#define Rr 4                      // y-rows per block (alignment: 4*304B = 19 lines)
#define ROWLEN (Rr * Wn)          // 304 floats per channel segment
#define PITCH_S 308               // u16 pitch (mult of 4 -> 8B-aligned ushort4 rows)
#define PITCH_W 304               // f32 pitch for wh channels (mult of 4 -> 16B-aligned)
#define BOX_TOTAL (Bn * Nn * 4)   // 4435968 floats
#define NWG (Bn * An * (Hn / Rr)) // 3648 = 8 * 456
#define CPX (NWG / 8)             // 456 blocks per XCD chunk
#define NT4 (CHn * (ROWLEN / 4))  // 6460 float4 staging loads per block
#define NCONF (ROWLEN * Cn)       // 24320 conf elements per block

typedef float floatx4 __attribute__((ext_vector_type(4)));

__device__ __forceinline__ float sigmoidf_(float x) {
    return 1.0f / (1.0f + __expf(-x));
}

__device__ __forceinline__ unsigned short f2bf(float f) {   // RNE f32->bf16
    unsigned u = __float_as_uint(f);
    return (unsigned short)((u + 0x7FFFu + ((u >> 16) & 1u)) >> 16);
}
__device__ __forceinline__ float bf2f(unsigned short h) {
    return __uint_as_float(((unsigned)h) << 16);
}

__launch_bounds__(512)
__global__ void yolo_kernel(const float* __restrict__ in, float* __restrict__ out) {
    // rows: ch0 -> 0, ch1 -> 1, ch4 -> 2, cls c -> 3+c
    __shared__ unsigned short s_sig[83 * PITCH_S];  // 51,128 B
    __shared__ float          s_wh[2 * PITCH_W];    //  2,432 B
    __shared__ unsigned short s_det[ROWLEN];        //    608 B

    // XCD-aware bijective swizzle (3648 % 8 == 0)
    const int raw = blockIdx.x;
    const int bid = (raw & 7) * CPX + (raw >> 3);

    const int yb = bid % (Hn / Rr);
    const int t  = bid / (Hn / Rr);
    const int a  = t % An;
    const int b  = t / An;
    const int y0 = yb * Rr;

    const float aw = (a == 0) ? 1.5f : ((a == 1) ? 2.375f : 5.0f);
    const float ah = (a == 0) ? 2.0f : ((a == 1) ? 4.5f   : 3.5f);

    const int tid = threadIdx.x;
    const float* __restrict__ src =
        in + ((size_t)(b * (An * CHn) + a * CHn)) * HW + (size_t)y0 * Wn;

    // ---- phase 1: stage 85 channels x 304 floats (64B-aligned 1216B bursts) ----
    for (int i = tid; i < NT4; i += 512) {
        const int ch = i / (ROWLEN / 4);        // /76
        const int q  = i % (ROWLEN / 4);
        const float4 v = *(const float4*)(src + (size_t)ch * HW + q * 4);
        if (ch == 2 || ch == 3) {
            float* d = &s_wh[(ch - 2) * PITCH_W + q * 4];
            d[0] = v.x; d[1] = v.y; d[2] = v.z; d[3] = v.w;
        } else {
            const int row = (ch < 2) ? ch : ((ch == 4) ? 2 : 3 + (ch - 5));
            ushort4 h;
            h.x = f2bf(v.x); h.y = f2bf(v.y); h.z = f2bf(v.z); h.w = f2bf(v.w);
            *(ushort4*)&s_sig[row * PITCH_S + q * 4] = h;   // 8B-aligned
        }
    }
    __syncthreads();

    const int n_base = a * HW + y0 * Wn;        // 304 consecutive n per block

    // ---- phase 2: boxes + det (304 lanes) ----
    if (tid < ROWLEN) {
        const int x  = tid % Wn;
        const int yy = y0 + tid / Wn;
        const float sx  = sigmoidf_(bf2f(s_sig[0 * PITCH_S + tid]));
        const float sy  = sigmoidf_(bf2f(s_sig[1 * PITCH_S + tid]));
        const float ew  = __expf(s_wh[0 * PITCH_W + tid]);
        const float eh  = __expf(s_wh[1 * PITCH_W + tid]);
        const float det = sigmoidf_(bf2f(s_sig[2 * PITCH_S + tid]));
        s_det[tid] = f2bf(det);

        const float bx = (sx + (float)x) * (1.0f / Wn);
        const float by = (sy + (float)yy) * (1.0f / Hn);
        const float bw = ew * aw * (1.0f / Wn);
        const float bh = eh * ah * (1.0f / Hn);
        const float bx1 = bx - 0.5f * bw;
        const float by1 = by - 0.5f * bh;

        const size_t n = (size_t)b * Nn + n_base + tid;
        floatx4 box;
        box.x = bx1; box.y = by1; box.z = bx1 + bw; box.w = by1 + bh;
        __builtin_nontemporal_store(box, (floatx4*)(out + n * 4));
    }
    __syncthreads();

    // ---- phase 3: confs, c-fastest -> coalesced nontemporal stores ----
    float* __restrict__ confs = out + BOX_TOTAL + ((size_t)b * Nn + n_base) * Cn;
    for (int i = tid; i < NCONF; i += 512) {
        const int s = i / Cn;
        const int c = i % Cn;
        const float v = sigmoidf_(bf2f(s_sig[(3 + c) * PITCH_S + s])) * bf2f(s_det[s]);
        __builtin_nontemporal_store(v, confs + i);
    }
}

extern "C" void kernel_launch(void* const* d_in, const int* in_sizes, int n_in,
                              void* d_out, int out_size, void* d_ws, size_t ws_size,
                              hipStream_t stream) {
    (void)in_sizes; (void)n_in; (void)d_ws; (void)ws_size; (void)out_size;
    const float* in = (const float*)d_in[0];
    float* out = (float*)d_out;
    yolo_kernel<<<NWG, 512, 0, stream>>>(in, out);
}

// Round 7
// 141.727 us; speedup vs baseline: 1.1243x; 1.1243x over previous
//
#include <hip/hip_runtime.h>

// YOLO layer: input [B, A*(5+C), H, W] fp32 -> (boxes [B,N,1,4], confs [B,N,C]) fp32
// B=64, A=3, C=80, H=W=76, N=A*H*W=17328
// d_out = boxes flat (B*N*4) then confs flat (B*N*C)
//
// R6->R7: revert to the proven R3 structure (1 row/block, f32 LDS, 256 thr,
// XCD swizzle, nt stores — 142.9us) + vectorize conf stores to float4
// (16B/lane, the only untouched stream: 355MB at 4B/lane previously).

#define Bn 64
#define An 3
#define Cn 80
#define Hn 76
#define Wn 76
#define HW (Hn * Wn)            // 5776
#define Nn (An * HW)            // 17328
#define CHn (5 + Cn)            // 85
#define PAD 77                  // LDS row pitch: gcd(77%32,32)=1 -> conflict-free scalar reads
#define BOX_TOTAL (Bn * Nn * 4) // 4435968 floats (div by 4 -> conf base 16B-aligned)
#define NWG (Bn * An * Hn)      // 14592 = 8 * 1824
#define CPX (NWG / 8)           // 1824 blocks per XCD chunk

typedef float floatx4 __attribute__((ext_vector_type(4)));

__device__ __forceinline__ float sigmoidf_(float x) {
    return 1.0f / (1.0f + __expf(-x));
}

__launch_bounds__(256)
__global__ void yolo_kernel(const float* __restrict__ in, float* __restrict__ out) {
    __shared__ float s_in[CHn * PAD];
    __shared__ float s_det[Wn];

    // XCD-aware bijective swizzle: each XCD owns a contiguous (b,a,y) chunk
    const int raw = blockIdx.x;
    const int bid = (raw & 7) * CPX + (raw >> 3);

    const int y = bid % Hn;
    const int t = bid / Hn;
    const int a = t % An;
    const int b = t / An;

    const float aw = (a == 0) ? 1.5f : ((a == 1) ? 2.375f : 5.0f);
    const float ah = (a == 0) ? 2.0f : ((a == 1) ? 4.5f   : 3.5f);

    const int tid = threadIdx.x;
    const float* __restrict__ src =
        in + ((size_t)(b * (An * CHn) + a * CHn)) * HW + (size_t)y * Wn;

    // ---- phase 1: stage 85 channels x 76 floats -> LDS (float4 coalesced) ----
    for (int i = tid; i < CHn * 19; i += 256) {
        const int ch = i / 19;
        const int q  = i % 19;
        const float4 v = *(const float4*)(src + (size_t)ch * HW + q * 4);
        float* d = &s_in[ch * PAD + q * 4];
        d[0] = v.x; d[1] = v.y; d[2] = v.z; d[3] = v.w;
    }
    __syncthreads();

    const int n_base = a * HW + y * Wn;

    // ---- phase 2: boxes + det (76 lanes) ----
    if (tid < Wn) {
        const int x = tid;
        const float sx  = sigmoidf_(s_in[0 * PAD + x]);
        const float sy  = sigmoidf_(s_in[1 * PAD + x]);
        const float ew  = __expf(s_in[2 * PAD + x]);
        const float eh  = __expf(s_in[3 * PAD + x]);
        const float det = sigmoidf_(s_in[4 * PAD + x]);
        s_det[x] = det;

        const float bx = (sx + (float)x) * (1.0f / Wn);
        const float by = (sy + (float)y) * (1.0f / Hn);
        const float bw = ew * aw * (1.0f / Wn);
        const float bh = eh * ah * (1.0f / Hn);
        const float bx1 = bx - 0.5f * bw;
        const float by1 = by - 0.5f * bh;

        const size_t n = (size_t)b * Nn + n_base + x;
        floatx4 box;
        box.x = bx1; box.y = by1; box.z = bx1 + bw; box.w = by1 + bh;
        __builtin_nontemporal_store(box, (floatx4*)(out + n * 4));
    }
    __syncthreads();

    // ---- phase 3: confs, float4 stores (16B/lane), c-fastest ----
    // i indexes groups of 4 consecutive c; addr = (5+c)*77+s, lanes span
    // c=4k (bank 20k mod 32, ~2.5-way) -- cheap per m136.
    float* __restrict__ confs = out + BOX_TOTAL + ((size_t)b * Nn + n_base) * Cn;
    for (int i = tid; i < (Wn * Cn) / 4; i += 256) {   // 1520 float4 per block
        const int s  = i / (Cn / 4);
        const int c4 = (i % (Cn / 4)) * 4;
        const float det = s_det[s];
        floatx4 v;
        v.x = sigmoidf_(s_in[(5 + c4 + 0) * PAD + s]) * det;
        v.y = sigmoidf_(s_in[(5 + c4 + 1) * PAD + s]) * det;
        v.z = sigmoidf_(s_in[(5 + c4 + 2) * PAD + s]) * det;
        v.w = sigmoidf_(s_in[(5 + c4 + 3) * PAD + s]) * det;
        __builtin_nontemporal_store(v, (floatx4*)(confs + i * 4));
    }
}

extern "C" void kernel_launch(void* const* d_in, const int* in_sizes, int n_in,
                              void* d_out, int out_size, void* d_ws, size_t ws_size,
                              hipStream_t stream) {
    (void)in_sizes; (void)n_in; (void)d_ws; (void)ws_size; (void)out_size;
    const float* in = (const float*)d_in[0];
    float* out = (float*)d_out;
    yolo_kernel<<<NWG, 256, 0, stream>>>(in, out);
}